// Round 3
// baseline (185.933 us; speedup 1.0000x reference)
//
#include <hip/hip_runtime.h>

// TrajectoryScore v3: LDS-decoupled loads.
// Global loads are pure unit-stride dwordx4 (lane i -> f4[base+i], the m13
// 6.3 TB/s copy pattern). Squared diffs computed elementwise on float4s,
// staged in LDS; the 3-float obs regrouping happens on LDS reads (cheap,
// 2-way bank aliasing = free). One tile per block, one __syncthreads.

constexpr int ELT_BATCH      = 64;
constexpr int OBS_PER_ELT    = 100000;
constexpr int F4_PER_SEG     = OBS_PER_ELT * 3 / 4;   // 75000
constexpr int BLOCK          = 256;
constexpr int BLOCKS_PER_SEG = 100;
constexpr int F4_PER_BLOCK   = F4_PER_SEG / BLOCKS_PER_SEG;  // 750 f4 = 3000 floats
constexpr int OBS_PER_BLOCK  = OBS_PER_ELT / BLOCKS_PER_SEG; // 1000 obs

__device__ __forceinline__ float wave_reduce_sum(float v) {
    #pragma unroll
    for (int off = 32; off > 0; off >>= 1)
        v += __shfl_down(v, off, 64);
    return v;
}

__global__ __launch_bounds__(BLOCK) void TrajectoryScore_58145267253396_kernel(
    const float4* __restrict__ pred4,
    const float4* __restrict__ obs4,
    const float*  __restrict__ h_arr,
    const float*  __restrict__ lam_arr,
    const float*  __restrict__ th_arr,
    float*        __restrict__ out)
{
    __shared__ float q2[F4_PER_BLOCK * 4];   // 3000 floats = 12 KB (squared diffs)

    const int seg     = blockIdx.x / BLOCKS_PER_SEG;
    const int blk     = blockIdx.x % BLOCKS_PER_SEG;
    const int tid     = threadIdx.x;
    const int f4_base = seg * F4_PER_SEG + blk * F4_PER_BLOCK;

    // --- Stage 1: issue all global loads (unit-stride dwordx4, deep MLP) ---
    float4 a[3], b[3];
    #pragma unroll
    for (int k = 0; k < 3; ++k) {
        const int idx = tid + k * BLOCK;          // k=0,1 always < 750; k=2 predicated
        if (idx < F4_PER_BLOCK) {
            a[k] = pred4[f4_base + idx];
            b[k] = obs4[f4_base + idx];
        }
    }

    // Per-segment params (overlaps the loads' latency).
    const float h    = h_arr[seg];
    const float lam  = lam_arr[seg];
    const float th   = th_arr[seg];
    const float coef = h * lam / (1.0f - __expf(-lam));
    const float omh  = 1.0f - h;
    const float nli  = -lam / th;

    // --- Stage 2: elementwise squared diff -> LDS ---
    #pragma unroll
    for (int k = 0; k < 3; ++k) {
        const int idx = tid + k * BLOCK;
        if (idx < F4_PER_BLOCK) {
            float4 d;
            d.x = a[k].x - b[k].x; d.y = a[k].y - b[k].y;
            d.z = a[k].z - b[k].z; d.w = a[k].w - b[k].w;
            float4 s;
            s.x = d.x * d.x; s.y = d.y * d.y; s.z = d.z * d.z; s.w = d.w * d.w;
            reinterpret_cast<float4*>(q2)[idx] = s;
        }
    }
    __syncthreads();

    // --- Stage 3: regroup 3 floats/obs from LDS, score, accumulate ---
    float ll = 0.0f;
    float hs = 0.0f;
    #pragma unroll
    for (int k = 0; k < 4; ++k) {
        const int t = tid + k * BLOCK;            // k=0..2 always < 1000; k=3 predicated
        if (t < OBS_PER_BLOCK) {
            const float s2    = q2[3 * t] + q2[3 * t + 1] + q2[3 * t + 2];
            const float e     = __expf(nli * s2);
            const float p_hit = coef * e;
            const float p     = p_hit + omh;
            const bool  close = s2 < th;
            const float lp    = __logf(p);
            ll += close ? lp : 0.0f;
            const float post  = p_hit / p;
            hs += (close && post > 0.95f) ? post : 0.0f;
        }
    }

    // --- Block reduction + per-segment atomics ---
    ll = wave_reduce_sum(ll);
    hs = wave_reduce_sum(hs);

    __shared__ float sll[BLOCK / 64];
    __shared__ float shs[BLOCK / 64];
    const int wave = tid >> 6;
    const int lane = tid & 63;
    if (lane == 0) { sll[wave] = ll; shs[wave] = hs; }
    __syncthreads();
    if (tid == 0) {
        float L = 0.0f, H = 0.0f;
        #pragma unroll
        for (int w = 0; w < BLOCK / 64; ++w) { L += sll[w]; H += shs[w]; }
        atomicAdd(&out[seg], L);
        atomicAdd(&out[ELT_BATCH + seg], H);
        atomicAdd(&out[2 * ELT_BATCH + seg], H);  // hits_raw == hits
    }
}

extern "C" void kernel_launch(void* const* d_in, const int* in_sizes, int n_in,
                              void* d_out, int out_size, void* d_ws, size_t ws_size,
                              hipStream_t stream) {
    const float4* pred4   = (const float4*)d_in[0];
    const float4* obs4    = (const float4*)d_in[1];
    const float*  h_arr   = (const float*)d_in[2];
    const float*  lam_arr = (const float*)d_in[3];
    const float*  th_arr  = (const float*)d_in[4];
    float* out = (float*)d_out;

    // Harness poisons d_out to 0xAA before timed replays — zero it ourselves.
    hipMemsetAsync(out, 0, out_size * sizeof(float), stream);

    dim3 grid(ELT_BATCH * BLOCKS_PER_SEG);   // 6400 blocks, 25/CU
    dim3 block(BLOCK);
    TrajectoryScore_58145267253396_kernel<<<grid, block, 0, stream>>>(
        pred4, obs4, h_arr, lam_arr, th_arr, out);
}

// Round 4
// 183.940 us; speedup vs baseline: 1.0108x; 1.0108x over previous
//
#include <hip/hip_runtime.h>
#include <stdint.h>

// TrajectoryScore v4: async DMA-to-LDS streaming.
// Rounds 1-3 established: ~63-67 us regardless of load shape, and identical
// time with inputs fully LLC-resident -> bottleneck is the CU-side VGPR-return
// load path (outstanding-miss limit), not HBM/LLC. This version streams raw
// pred/obs chunks into LDS via global_load_lds (width 16, wave-uniform base +
// lane*16 — layout is contiguous so the constraint is natural), which uses the
// deep DMA queue (m97: ~13 TB/s aggregate staging in GEMM).

constexpr int ELT_BATCH      = 64;
constexpr int OBS_PER_ELT    = 100000;
constexpr int F4_PER_SEG     = OBS_PER_ELT * 3 / 4;          // 75000
constexpr int BLOCK          = 256;
constexpr int BLOCKS_PER_SEG = 100;
constexpr int F4_PER_BLOCK   = F4_PER_SEG / BLOCKS_PER_SEG;  // 750 f4 = 3000 floats
constexpr int OBS_PER_BLOCK  = OBS_PER_ELT / BLOCKS_PER_SEG; // 1000 obs

#define GLOBAL_AS __attribute__((address_space(1)))
#define LDS_AS    __attribute__((address_space(3)))

__device__ __forceinline__ void dma16(const float4* g, float* lds_base_elem) {
    // One 16B element per lane; LDS dest = wave-uniform base + lane*16.
    __builtin_amdgcn_global_load_lds((const GLOBAL_AS void*)g,
                                     (LDS_AS void*)lds_base_elem,
                                     16, 0, 0);
}

__device__ __forceinline__ float wave_reduce_sum(float v) {
    #pragma unroll
    for (int off = 32; off > 0; off >>= 1)
        v += __shfl_down(v, off, 64);
    return v;
}

__global__ __launch_bounds__(BLOCK) void TrajectoryScore_58145267253396_kernel(
    const float4* __restrict__ pred4,
    const float4* __restrict__ obs4,
    const float*  __restrict__ h_arr,
    const float*  __restrict__ lam_arr,
    const float*  __restrict__ th_arr,
    float*        __restrict__ out)
{
    __shared__ float sp[F4_PER_BLOCK * 4];   // 12 KB raw pred chunk
    __shared__ float so[F4_PER_BLOCK * 4];   // 12 KB raw obs chunk

    const int seg     = blockIdx.x / BLOCKS_PER_SEG;
    const int blk     = blockIdx.x % BLOCKS_PER_SEG;
    const int tid     = threadIdx.x;
    const int wave    = tid >> 6;
    const int f4_base = seg * F4_PER_SEG + blk * F4_PER_BLOCK;

    // --- Stage 1: DMA the chunk into LDS (6 wave-instructions, deep queue) ---
    #pragma unroll
    for (int k = 0; k < 3; ++k) {
        const int idx = k * BLOCK + tid;                // lane-contiguous
        const int wbase = (k * BLOCK + wave * 64) * 4;  // wave-uniform LDS base (floats)
        if (idx < F4_PER_BLOCK) {
            dma16(&pred4[f4_base + idx], &sp[wbase]);
            dma16(&obs4[f4_base + idx],  &so[wbase]);
        }
    }

    // Per-segment params (overlap DMA latency).
    const float h    = h_arr[seg];
    const float lam  = lam_arr[seg];
    const float th   = th_arr[seg];
    const float coef = h * lam / (1.0f - __expf(-lam));
    const float omh  = 1.0f - h;
    const float nli  = -lam / th;

    __syncthreads();   // drains vmcnt (DMA tracked by vmcnt) + barrier

    // --- Stage 2: score 1000 obs from LDS ---
    float ll = 0.0f;
    float hs = 0.0f;
    #pragma unroll
    for (int k = 0; k < 4; ++k) {
        const int t = k * BLOCK + tid;                  // k=3 partial (tail 232)
        if (t < OBS_PER_BLOCK) {
            const float dx = sp[3 * t]     - so[3 * t];
            const float dy = sp[3 * t + 1] - so[3 * t + 1];
            const float dz = sp[3 * t + 2] - so[3 * t + 2];
            const float s2 = dx * dx + dy * dy + dz * dz;
            const float e     = __expf(nli * s2);
            const float p_hit = coef * e;
            const float p     = p_hit + omh;
            const bool  close = s2 < th;
            const float lp    = __logf(p);
            ll += close ? lp : 0.0f;
            const float post  = p_hit / p;
            hs += (close && post > 0.95f) ? post : 0.0f;
        }
    }

    // --- Block reduction + per-segment atomics ---
    ll = wave_reduce_sum(ll);
    hs = wave_reduce_sum(hs);

    __shared__ float sll[BLOCK / 64];
    __shared__ float shs[BLOCK / 64];
    const int lane = tid & 63;
    if (lane == 0) { sll[wave] = ll; shs[wave] = hs; }
    __syncthreads();
    if (tid == 0) {
        float L = 0.0f, H = 0.0f;
        #pragma unroll
        for (int w = 0; w < BLOCK / 64; ++w) { L += sll[w]; H += shs[w]; }
        atomicAdd(&out[seg], L);
        atomicAdd(&out[ELT_BATCH + seg], H);
        atomicAdd(&out[2 * ELT_BATCH + seg], H);  // hits_raw == hits
    }
}

extern "C" void kernel_launch(void* const* d_in, const int* in_sizes, int n_in,
                              void* d_out, int out_size, void* d_ws, size_t ws_size,
                              hipStream_t stream) {
    const float4* pred4   = (const float4*)d_in[0];
    const float4* obs4    = (const float4*)d_in[1];
    const float*  h_arr   = (const float*)d_in[2];
    const float*  lam_arr = (const float*)d_in[3];
    const float*  th_arr  = (const float*)d_in[4];
    float* out = (float*)d_out;

    // Harness poisons d_out to 0xAA before timed replays — zero it ourselves.
    hipMemsetAsync(out, 0, out_size * sizeof(float), stream);

    dim3 grid(ELT_BATCH * BLOCKS_PER_SEG);   // 6400 blocks, LDS-capped 6/CU
    dim3 block(BLOCK);
    TrajectoryScore_58145267253396_kernel<<<grid, block, 0, stream>>>(
        pred4, obs4, h_arr, lam_arr, th_arr, out);
}